// Round 6
// baseline (278.255 us; speedup 1.0000x reference)
//
#include <hip/hip_runtime.h>
#include <cstdint>

static constexpr int S = 1024;
static constexpr int T = 32;
static constexpr float L2E  = 1.4426950408889634f;  // log2(e)
static constexpr float LN2f = 0.6931471805599453f;  // ln(2)

typedef __attribute__((ext_vector_type(8)))  short  short8;
typedef __attribute__((ext_vector_type(16))) float  float16;

union Frag { unsigned u[4]; short8 s; };

__global__ void crf_zero(float* ws) {
  ws[0] = 0.0f; ws[1] = 0.0f; ((unsigned*)ws)[2] = 0u;
}

__device__ __forceinline__ float bcast_lane(float v, int k) {
  return __uint_as_float((unsigned)__builtin_amdgcn_readlane((int)__float_as_uint(v), k));
}

// single-instruction rounded pack: two f32 -> bf16x2 (lo = first arg).
__device__ __forceinline__ unsigned cvtpk(float lo, float hi) {
  unsigned r;
  asm("v_cvt_pk_bf16_f32 %0, %1, %2" : "=v"(r) : "v"(lo), "v"(hi));
  return r;
}

// async global->LDS, 16 B per lane: dest = wave-uniform base + lane*16.
__device__ __forceinline__ void gload16(const float* src, float* dst) {
  __builtin_amdgcn_global_load_lds(
      (const __attribute__((address_space(1))) unsigned int*)(src),
      (__attribute__((address_space(3))) unsigned int*)(dst),
      16, 0, 0);
}

// sigma: fixed row permutation mapping MFMA C-layout row slots onto B-operand
// row slots (swaps 4-blocks 1<->2 within each 16). With A pre-permuted
// (A'[m][k] = X[m][sig(k)]) the product is exact and D's packed pairs ARE the
// next B-operand - no lane data movement.
__device__ __forceinline__ int sig(int k) {
  int g2 = (k >> 2) & 3;
  if (g2 == 1) g2 = 2; else if (g2 == 2) g2 = 1;
  return (k & ~12) | (g2 << 2);
}

// Block = one batch (512 thr = 8 waves). Active range (head, tail] split into
// 8 equal chunks; wave w folds its chunk into a 32x32 matrix via MFMA in the
// linear 2^x domain. KEY (R6): the diagonal is applied on the A OPERAND -
// A_j = diag(g_j)*P^T scales row m=n of the fragment by the single scalar
// g_j[n] = 2^(em[j][n]*log2e). So per fold: 1 broadcast ds_read_b32 (own
// column) instead of 4 ds_read_b128, the 16 scale-muls move OFF the MFMA
// dependency chain (A-build is independent of M, pipelined 1 fold ahead),
// em stays RAW in LDS (no convert pass; numerator reads em directly), and
// the fold fits the 85-reg budget without spill.
__global__ __launch_bounds__(512, 6) void crf_main(
    const float* __restrict__ em, const int* __restrict__ tags,
    const int* __restrict__ mask, const float* __restrict__ startT,
    const float* __restrict__ trans, const float* __restrict__ endT,
    float* __restrict__ ws, float* __restrict__ out, int B)
{
  // 17408 B pool: fold phase = 8 waves x 512 f32 raw-em windows (16384 B);
  // publish/scan phase = 8 chunk mats x 544 u32 (17408 B). Barrier-separated.
  __shared__ __align__(16) unsigned s_pool[8 * 544];
  __shared__ float s_trans[1024];                      // 4 KiB
  __shared__ short s_tags[1024];                       // 2 KiB
  __shared__ unsigned long long s_mb[17];
  __shared__ int   s_head, s_tail, s_cnt, s_K[8];
  __shared__ float s_num[8];

  const int tid = threadIdx.x;
  const int l   = tid & 63;
  const int wv  = tid >> 6;
  const int b   = blockIdx.x;
  const int n   = l & 31;        // MFMA column / tag index
  const int h   = l >> 5;        // lane half

  const float* emb   = em   + (size_t)b * S * T;
  const int*   maskb = mask + (size_t)b * S;
  const int*   tagsb = tags + (size_t)b * S;

  // ---- cooperative staging: tags, trans, mask ballots ----
  for (int i = tid; i < 1024; i += 512) {
    s_tags[i]  = (short)tagsb[i];
    s_trans[i] = trans[i];
  }
  {
    unsigned long long b0 = __ballot(maskb[wv * 128 + l] != 0);
    unsigned long long b1 = __ballot(maskb[wv * 128 + 64 + l] != 0);
    if (l == 0) { s_mb[2 * wv] = b0; s_mb[2 * wv + 1] = b1; }
    if (tid == 0) s_mb[16] = 0ull;
  }

  // ---- unscaled A base: bs[16] = exp(trans[sig(slot)][n]) as f32 ----
  float bsl[8], bsh[8];
  #pragma unroll
  for (int p = 0; p < 4; ++p) {
    int k0 = 8 * h + 2 * p;
    bsl[2 * p + 0] = exp2f(trans[sig(k0 + 0)      * T + n] * L2E);
    bsl[2 * p + 1] = exp2f(trans[sig(k0 + 1)      * T + n] * L2E);
    bsh[2 * p + 0] = exp2f(trans[sig(16 + k0 + 0) * T + n] * L2E);
    bsh[2 * p + 1] = exp2f(trans[sig(16 + k0 + 1) * T + n] * L2E);
  }
  __syncthreads();

  if (wv == 0) {
    int first = 0x7fffffff, last = -1, pc = 0;
    if (l < 16) {
      unsigned long long w = s_mb[l];
      if (w) {
        first = 64 * l + (int)__builtin_ctzll(w);
        last  = 64 * l + 63 - (int)__builtin_clzll(w);
        pc    = (int)__builtin_popcountll(w);
      }
    }
    #pragma unroll
    for (int d = 1; d < 64; d <<= 1) {
      first = min(first, __shfl_xor(first, d));
      last  = max(last,  __shfl_xor(last,  d));
      pc   += __shfl_xor(pc, d);
    }
    if (l == 0) { s_head = first; s_tail = last; s_cnt = pc; }
  }
  __syncthreads();
  const int cnt  = s_cnt;
  const int head = (cnt > 0) ? s_head : 0;
  const int tail = (cnt > 0) ? s_tail : 0;

  // ---- equal-split chunk for this wave ----
  const int span = tail - head;
  const int Lc   = (span + 7) >> 3;
  const int c0   = head + 1 + wv * Lc;
  const int c1   = min(c0 + Lc, tail + 1);

  float* bcur = (float*)s_pool + wv * 512;   // ping-pong 8-step raw-em windows
  float* bnxt = bcur + 256;

  Frag Blo, Bhi;                    // running M in sigma-storage, init = I
  #pragma unroll
  for (int p = 0; p < 4; ++p) {
    int k0 = 8 * h + 2 * p;
    Blo.u[p] = ((sig(k0) == n)          ? 0x3F80u : 0u) |
               ((sig(k0 + 1) == n)      ? 0x3F800000u : 0u);
    Bhi.u[p] = ((sig(16 + k0) == n)     ? 0x3F80u : 0u) |
               ((sig(16 + k0 + 1) == n) ? 0x3F800000u : 0u);
  }
  int   Kacc  = 0;
  float numer = 0.0f;
  const float16 Zv = {0,0,0,0,0,0,0,0,0,0,0,0,0,0,0,0};

  // build A_j = diag(g_j)*P^T frags: one scalar g per lane, off-chain
#define ABUILD(AL, AH, JJ) do {                                              \
    float gn = exp2f(gp[(JJ) * 32 + n] * L2E);                               \
    AL.u[0] = cvtpk(bsl[0] * gn, bsl[1] * gn);                               \
    AL.u[1] = cvtpk(bsl[2] * gn, bsl[3] * gn);                               \
    AL.u[2] = cvtpk(bsl[4] * gn, bsl[5] * gn);                               \
    AL.u[3] = cvtpk(bsl[6] * gn, bsl[7] * gn);                               \
    AH.u[0] = cvtpk(bsh[0] * gn, bsh[1] * gn);                               \
    AH.u[1] = cvtpk(bsh[2] * gn, bsh[3] * gn);                               \
    AH.u[2] = cvtpk(bsh[4] * gn, bsh[5] * gn);                               \
    AH.u[3] = cvtpk(bsh[6] * gn, bsh[7] * gn);                               \
  } while (0)

  // chain step using prebuilt A; optionally prebuilds A for fold JN
#define FOLDP(AL, AH, NL, NH, JN, RSC) do {                                  \
    float16 D = __builtin_amdgcn_mfma_f32_32x32x16_bf16(AL.s, Blo.s, Zv, 0, 0, 0); \
    D = __builtin_amdgcn_mfma_f32_32x32x16_bf16(AH.s, Bhi.s, D, 0, 0, 0);    \
    if ((JN) >= 0) ABUILD(NL, NH, JN);                                       \
    if (RSC) {                                                               \
      float mx = fmaxf(fmaxf(fmaxf(D[0], D[1]), fmaxf(D[2], D[3])),          \
                       fmaxf(fmaxf(D[4], D[5]), fmaxf(D[6], D[7])));         \
      mx = fmaxf(mx, fmaxf(fmaxf(fmaxf(D[8], D[9]),  fmaxf(D[10], D[11])),   \
                           fmaxf(fmaxf(D[12], D[13]), fmaxf(D[14], D[15]))));\
      mx = fmaxf(mx, __shfl_xor(mx, 32));   /* column-0 max (valid bound) */ \
      mx = __uint_as_float((unsigned)__builtin_amdgcn_readfirstlane(         \
               (int)__float_as_uint(mx)));                                   \
      int E = (int)((__float_as_uint(mx) >> 23) & 0xffu);                    \
      float sc = __uint_as_float((unsigned)(254 - E) << 23);                 \
      Kacc += E - 127;                                                       \
      _Pragma("unroll")                                                      \
      for (int q_ = 0; q_ < 16; ++q_) D[q_] *= sc;                           \
    }                                                                        \
    Blo.u[0] = cvtpk(D[0],  D[1]);  Blo.u[1] = cvtpk(D[2],  D[3]);           \
    Blo.u[2] = cvtpk(D[4],  D[5]);  Blo.u[3] = cvtpk(D[6],  D[7]);           \
    Bhi.u[0] = cvtpk(D[8],  D[9]);  Bhi.u[1] = cvtpk(D[10], D[11]);          \
    Bhi.u[2] = cvtpk(D[12], D[13]); Bhi.u[3] = cvtpk(D[14], D[15]);          \
  } while (0)

  // prologue: async-stage first 8-step window (raw em)
  if (c0 < c1) {
    const int base = min(c0, S - 8);
    gload16(emb + (size_t)base * T + 4 * l, bcur);
  }

  for (int j0 = c0; j0 < c1; j0 += 8) {
    const int ns   = min(8, c1 - j0);
    const int base = min(j0, S - 8);
    const int d    = j0 - base;          // shift of j0 within loaded window

    // wait this wave's async load (raw em usable directly)
    asm volatile("s_waitcnt vmcnt(0)" ::: "memory");

    // issue next window's async load now; folds below hide its latency
    if (j0 + 8 < c1) {
      const int nb = min(j0 + 8, S - 8);
      gload16(emb + (size_t)nb * T + 4 * l, bnxt);
    }

    const float* gp = bcur + d * 32;

    // 8-bit applied-mask at arbitrary offset j0 (funnel over ballot words)
    const int w = j0 >> 6, o = j0 & 63;
    unsigned long long bits = s_mb[w] >> o;
    if (o) bits |= s_mb[w + 1] << (64 - o);
    unsigned eff = (unsigned)(bits & 0xFFull) & (unsigned)((1u << ns) - 1u);

    // numerator: lanes 0..ns-1 take one step each (raw em, no log roundtrip)
    if (l < ns && ((eff >> l) & 1u)) {
      int j  = j0 + l;
      int tg = (int)s_tags[j], tp = (int)s_tags[j - 1];
      numer += s_trans[tp * T + tg] + gp[l * 32 + tg];
    }

    if (eff == 0xFFu) {
      Frag Xl, Xh, Yl, Yh;
      ABUILD(Xl, Xh, 0);
      FOLDP(Xl, Xh, Yl, Yh, 1, false);
      FOLDP(Yl, Yh, Xl, Xh, 2, false);
      FOLDP(Xl, Xh, Yl, Yh, 3, false);
      FOLDP(Yl, Yh, Xl, Xh, 4, false);
      FOLDP(Xl, Xh, Yl, Yh, 5, false);
      FOLDP(Yl, Yh, Xl, Xh, 6, false);
      FOLDP(Xl, Xh, Yl, Yh, 7, false);
      FOLDP(Yl, Yh, Xl, Xh, -1, true);
    } else {
      for (int jj = 0; jj < ns; ++jj)
        if ((eff >> jj) & 1u) {
          Frag Xl, Xh;
          ABUILD(Xl, Xh, jj);
          FOLDP(Xl, Xh, Xl, Xh, -1, true);
        }
    }

    float* tmp = bcur; bcur = bnxt; bnxt = tmp;
  }
#undef FOLDP
#undef ABUILD

  // ---- all folds done before the mats overlay is written (union hazard) ----
  __syncthreads();

  // ---- publish chunk matrix (packed bf16 row pairs, sigma-unscrambled) ----
  {
    unsigned* mw = s_pool + wv * 544;
    #pragma unroll
    for (int p = 0; p < 4; ++p) {
      mw[(sig(8 * h + 2 * p)      >> 1) * 34 + n] = Blo.u[p];
      mw[(sig(16 + 8 * h + 2 * p) >> 1) * 34 + n] = Bhi.u[p];
    }
  }
  #pragma unroll
  for (int d = 1; d < 64; d <<= 1) numer += __shfl_xor(numer, d);
  if (l == 0) { s_num[wv] = numer; s_K[wv] = Kacc; }
  __syncthreads();

  // ---- phase 2: wave 0 scans the 8 chunk matrices ----
  if (wv == 0) {
    const int t = n;
    const float em0 = emb[head * T + t];
    float sc0 = (startT[t] + em0) * L2E;
    float m0 = sc0;
    #pragma unroll
    for (int d = 1; d < 32; d <<= 1) m0 = fmaxf(m0, __shfl_xor(m0, d));
    float e = exp2f(sc0 - m0);
    float Mtot = m0;

    const unsigned sh = (t & 1) ? 0u : 16u;   // select row-half of packed word
    for (int c = 0; c < 8; ++c) {
      const unsigned* mw = s_pool + c * 544 + (t >> 1) * 34;
      float acc = 0.0f;
      #pragma unroll
      for (int q2 = 0; q2 < 16; ++q2) {
        uint2 w2 = *(const uint2*)(mw + 2 * q2);
        float vlo = __uint_as_float((w2.x << sh) & 0xFFFF0000u);
        float vhi = __uint_as_float((w2.y << sh) & 0xFFFF0000u);
        acc = fmaf(vlo, bcast_lane(e, 2 * q2), acc);
        acc = fmaf(vhi, bcast_lane(e, 2 * q2 + 1), acc);
      }
      e = acc;
      Mtot += (float)s_K[c];
      float mx = e;
      #pragma unroll
      for (int d = 1; d < 32; d <<= 1) mx = fmaxf(mx, __shfl_xor(mx, d));
      int E = (int)((__float_as_uint(mx) >> 23) & 0xffu);
      e *= __uint_as_float((unsigned)(254 - E) << 23);
      Mtot += (float)(E - 127);
    }

    float fv = e * exp2f(endT[t] * L2E);
    #pragma unroll
    for (int d = 1; d < 32; d <<= 1) fv += __shfl_xor(fv, d);
    float denom = (Mtot + log2f(fv)) * LN2f;

    if (l == 0) {
      if (cnt > 0) {
        float ntot = 0.0f;
        for (int wq = 0; wq < 8; ++wq) ntot += s_num[wq];
        int th = (int)s_tags[head], tt = (int)s_tags[tail];
        ntot += startT[th] + bcast_lane(em0, th) + endT[tt];
        atomicAdd(&ws[0], (denom - ntot) / ((float)cnt + 1e-6f));
        atomicAdd(&ws[1], 1.0f);
      }
      __threadfence();
      unsigned done = atomicAdd((unsigned*)ws + 2, 1u);
      if (done == (unsigned)(B - 1)) {
        __threadfence();
        out[0] = ws[0] / (ws[1] + 1e-6f);
      }
    }
  }
}

extern "C" void kernel_launch(void* const* d_in, const int* in_sizes, int n_in,
                              void* d_out, int out_size, void* d_ws, size_t ws_size,
                              hipStream_t stream) {
  const float* em     = (const float*)d_in[0];
  const int*   tags   = (const int*)d_in[1];
  const int*   mask   = (const int*)d_in[2];
  const float* startT = (const float*)d_in[3];
  const float* trans  = (const float*)d_in[4];
  const float* endT   = (const float*)d_in[5];
  float* out = (float*)d_out;
  float* ws  = (float*)d_ws;

  const int B = in_sizes[0] / (S * T);

  crf_zero<<<1, 1, 0, stream>>>(ws);
  crf_main<<<B, 512, 0, stream>>>(em, tags, mask, startT, trans, endT, ws, out, B);
}

// Round 7
// 271.098 us; speedup vs baseline: 1.0264x; 1.0264x over previous
//
#include <hip/hip_runtime.h>
#include <cstdint>

static constexpr int S = 1024;
static constexpr int T = 32;
static constexpr float L2E  = 1.4426950408889634f;  // log2(e)
static constexpr float LN2f = 0.6931471805599453f;  // ln(2)

typedef __attribute__((ext_vector_type(8)))  short  short8;
typedef __attribute__((ext_vector_type(16))) float  float16;

union Frag { unsigned u[4]; short8 s; };

__global__ void crf_zero(float* ws) {
  ws[0] = 0.0f; ws[1] = 0.0f; ((unsigned*)ws)[2] = 0u;
}

__device__ __forceinline__ float bcast_lane(float v, int k) {
  return __uint_as_float((unsigned)__builtin_amdgcn_readlane((int)__float_as_uint(v), k));
}

// single-instruction rounded pack: two f32 -> bf16x2 (lo = first arg).
__device__ __forceinline__ unsigned cvtpk(float lo, float hi) {
  unsigned r;
  asm("v_cvt_pk_bf16_f32 %0, %1, %2" : "=v"(r) : "v"(lo), "v"(hi));
  return r;
}

// async global->LDS, 16 B per lane: dest = wave-uniform base + lane*16.
__device__ __forceinline__ void gload16(const float* src, float* dst) {
  __builtin_amdgcn_global_load_lds(
      (const __attribute__((address_space(1))) unsigned int*)(src),
      (__attribute__((address_space(3))) unsigned int*)(dst),
      16, 0, 0);
}

// sigma: fixed row permutation mapping MFMA C-layout row slots onto B-operand
// row slots (swaps 4-blocks 1<->2 within each 16). With A pre-permuted
// (A'[m][k] = X[m][sig(k)]) the product is exact and D's packed pairs ARE the
// next B-operand - no lane data movement.
__device__ __forceinline__ int sig(int k) {
  int g2 = (k >> 2) & 3;
  if (g2 == 1) g2 = 2; else if (g2 == 2) g2 = 1;
  return (k & ~12) | (g2 << 2);
}

// Block = one batch (512 thr = 8 waves). Active range (head, tail] split into
// 8 equal chunks; wave w folds its chunk into a 32x32 matrix via MFMA in the
// linear 2^x domain (M <- diag(g_j) P^T M). em staged async via
// global_load_lds into wave-private double-buffered 8-step windows; the
// g-window pool and the chunk-matrix pool are temporally disjoint -> overlaid
// in one LDS union (24 KB total).
// R7: __launch_bounds__(512,6) = 85-reg budget. The fold's live set is ~79
// regs (D 16 + zeroC 16 + A 8 + B 8 + gw 16 + addr); R5's (512,8)=64-reg cap
// forced ~15 spilled regs (WRITE_SIZE 14.4 MB = 27 B/thread) plus per-fold
// zero-remat / acc-move traffic (~60 phantom VALU ops/fold measured).
__global__ __launch_bounds__(512, 6) void crf_main(
    const float* __restrict__ em, const int* __restrict__ tags,
    const int* __restrict__ mask, const float* __restrict__ startT,
    const float* __restrict__ trans, const float* __restrict__ endT,
    float* __restrict__ ws, float* __restrict__ out, int B)
{
  // 17408 B pool: fold phase = 8 waves x 512 f32 g-windows (16384 B);
  // publish/scan phase = 8 chunk mats x 544 u32 (17408 B). Barrier-separated.
  __shared__ __align__(16) unsigned s_pool[8 * 544];
  __shared__ float s_trans[1024];                      // 4 KiB
  __shared__ short s_tags[1024];                       // 2 KiB
  __shared__ unsigned long long s_mb[17];
  __shared__ int   s_head, s_tail, s_cnt, s_K[8];
  __shared__ float s_num[8];

  const int tid = threadIdx.x;
  const int l   = tid & 63;
  const int wv  = tid >> 6;
  const int b   = blockIdx.x;
  const int n   = l & 31;        // MFMA column / tag index
  const int h   = l >> 5;        // lane half

  const float* emb   = em   + (size_t)b * S * T;
  const int*   maskb = mask + (size_t)b * S;
  const int*   tagsb = tags + (size_t)b * S;

  // ---- cooperative staging: tags, trans, mask ballots ----
  for (int i = tid; i < 1024; i += 512) {
    s_tags[i]  = (short)tagsb[i];
    s_trans[i] = trans[i];
  }
  {
    unsigned long long b0 = __ballot(maskb[wv * 128 + l] != 0);
    unsigned long long b1 = __ballot(maskb[wv * 128 + 64 + l] != 0);
    if (l == 0) { s_mb[2 * wv] = b0; s_mb[2 * wv + 1] = b1; }
    if (tid == 0) s_mb[16] = 0ull;
  }

  // ---- A' = sigma-permuted P^T as bf16 frags (lane: m=n, k-slot=8h+2p+par) ----
  Frag Alo, Ahi;
  #pragma unroll
  for (int p = 0; p < 4; ++p) {
    int k0 = 8 * h + 2 * p;
    Alo.u[p] = cvtpk(exp2f(trans[sig(k0 + 0)      * T + n] * L2E),
                     exp2f(trans[sig(k0 + 1)      * T + n] * L2E));
    Ahi.u[p] = cvtpk(exp2f(trans[sig(16 + k0 + 0) * T + n] * L2E),
                     exp2f(trans[sig(16 + k0 + 1) * T + n] * L2E));
  }
  __syncthreads();

  if (wv == 0) {
    int first = 0x7fffffff, last = -1, pc = 0;
    if (l < 16) {
      unsigned long long w = s_mb[l];
      if (w) {
        first = 64 * l + (int)__builtin_ctzll(w);
        last  = 64 * l + 63 - (int)__builtin_clzll(w);
        pc    = (int)__builtin_popcountll(w);
      }
    }
    #pragma unroll
    for (int d = 1; d < 64; d <<= 1) {
      first = min(first, __shfl_xor(first, d));
      last  = max(last,  __shfl_xor(last,  d));
      pc   += __shfl_xor(pc, d);
    }
    if (l == 0) { s_head = first; s_tail = last; s_cnt = pc; }
  }
  __syncthreads();
  const int cnt  = s_cnt;
  const int head = (cnt > 0) ? s_head : 0;
  const int tail = (cnt > 0) ? s_tail : 0;

  // ---- equal-split chunk for this wave ----
  const int span = tail - head;
  const int Lc   = (span + 7) >> 3;
  const int c0   = head + 1 + wv * Lc;
  const int c1   = min(c0 + Lc, tail + 1);

  float* bcur = (float*)s_pool + wv * 512;   // ping-pong 8-step windows (wave-private)
  float* bnxt = bcur + 256;

  Frag Blo, Bhi;                    // running M in sigma-storage, init = I
  #pragma unroll
  for (int p = 0; p < 4; ++p) {
    int k0 = 8 * h + 2 * p;
    Blo.u[p] = ((sig(k0) == n)          ? 0x3F80u : 0u) |
               ((sig(k0 + 1) == n)      ? 0x3F800000u : 0u);
    Bhi.u[p] = ((sig(16 + k0) == n)     ? 0x3F80u : 0u) |
               ((sig(16 + k0 + 1) == n) ? 0x3F800000u : 0u);
  }
  int   Kacc  = 0;
  float numer = 0.0f;
  const float16 Zv = {0,0,0,0,0,0,0,0,0,0,0,0,0,0,0,0};

#define FOLD(JJ, RSC) do {                                                   \
    const float4* gw = (const float4*)(gp + (JJ) * 32);                      \
    float4 wa = gw[h], wb = gw[h + 2], wc = gw[h + 4], wd = gw[h + 6];       \
    float16 D = __builtin_amdgcn_mfma_f32_32x32x16_bf16(Alo.s, Blo.s, Zv, 0, 0, 0); \
    D = __builtin_amdgcn_mfma_f32_32x32x16_bf16(Ahi.s, Bhi.s, D, 0, 0, 0);   \
    D[0]  *= wa.x; D[1]  *= wa.y; D[2]  *= wa.z; D[3]  *= wa.w;              \
    D[4]  *= wb.x; D[5]  *= wb.y; D[6]  *= wb.z; D[7]  *= wb.w;              \
    D[8]  *= wc.x; D[9]  *= wc.y; D[10] *= wc.z; D[11] *= wc.w;              \
    D[12] *= wd.x; D[13] *= wd.y; D[14] *= wd.z; D[15] *= wd.w;              \
    if (RSC) {                                                               \
      float mx = fmaxf(fmaxf(fmaxf(D[0], D[1]), fmaxf(D[2], D[3])),          \
                       fmaxf(fmaxf(D[4], D[5]), fmaxf(D[6], D[7])));         \
      mx = fmaxf(mx, fmaxf(fmaxf(fmaxf(D[8], D[9]),  fmaxf(D[10], D[11])),   \
                           fmaxf(fmaxf(D[12], D[13]), fmaxf(D[14], D[15]))));\
      mx = fmaxf(mx, __shfl_xor(mx, 32));   /* column-0 max (valid bound) */ \
      mx = __uint_as_float((unsigned)__builtin_amdgcn_readfirstlane(         \
               (int)__float_as_uint(mx)));                                   \
      int E = (int)((__float_as_uint(mx) >> 23) & 0xffu);                    \
      float sc = __uint_as_float((unsigned)(254 - E) << 23);                 \
      Kacc += E - 127;                                                       \
      _Pragma("unroll")                                                      \
      for (int q_ = 0; q_ < 16; ++q_) D[q_] *= sc;                           \
    }                                                                        \
    Blo.u[0] = cvtpk(D[0],  D[1]);  Blo.u[1] = cvtpk(D[2],  D[3]);           \
    Blo.u[2] = cvtpk(D[4],  D[5]);  Blo.u[3] = cvtpk(D[6],  D[7]);           \
    Bhi.u[0] = cvtpk(D[8],  D[9]);  Bhi.u[1] = cvtpk(D[10], D[11]);          \
    Bhi.u[2] = cvtpk(D[12], D[13]); Bhi.u[3] = cvtpk(D[14], D[15]);          \
  } while (0)

  // prologue: async-stage first 8-step window
  if (c0 < c1) {
    const int base = min(c0, S - 8);
    gload16(emb + (size_t)base * T + 4 * l, bcur);
  }

  for (int j0 = c0; j0 < c1; j0 += 8) {
    const int ns   = min(8, c1 - j0);
    const int base = min(j0, S - 8);
    const int d    = j0 - base;          // shift of j0 within loaded window

    // wait this wave's async load, then convert em -> g = 2^em in place
    // (each lane converts exactly the 16 B it loaded; wave-private buffer)
    asm volatile("s_waitcnt vmcnt(0)" ::: "memory");
    {
      float4 r = ((const float4*)bcur)[l];
      r.x = exp2f(r.x * L2E); r.y = exp2f(r.y * L2E);
      r.z = exp2f(r.z * L2E); r.w = exp2f(r.w * L2E);
      ((float4*)bcur)[l] = r;
    }

    // issue next window's async load now; folds below hide its latency
    if (j0 + 8 < c1) {
      const int nb = min(j0 + 8, S - 8);
      gload16(emb + (size_t)nb * T + 4 * l, bnxt);
    }

    const float* gp = bcur + d * 32;

    // 8-bit applied-mask at arbitrary offset j0 (funnel over ballot words)
    const int w = j0 >> 6, o = j0 & 63;
    unsigned long long bits = s_mb[w] >> o;
    if (o) bits |= s_mb[w + 1] << (64 - o);
    unsigned eff = (unsigned)(bits & 0xFFull) & (unsigned)((1u << ns) - 1u);

    // numerator: lanes 0..ns-1 take one step each (em recovered from f32 g)
    if (l < ns && ((eff >> l) & 1u)) {
      int j  = j0 + l;
      int tg = (int)s_tags[j], tp = (int)s_tags[j - 1];
      float gval = gp[l * 32 + tg];
      numer += s_trans[tp * T + tg] + log2f(gval) * LN2f;
    }

    if (eff == 0xFFu) {
      #pragma unroll
      for (int jj = 0; jj < 8; ++jj) FOLD(jj, (jj == 7));
    } else {
      for (int jj = 0; jj < ns; ++jj)
        if ((eff >> jj) & 1u) FOLD(jj, true);
    }

    float* tmp = bcur; bcur = bnxt; bnxt = tmp;
  }
#undef FOLD

  // ---- all folds done before the mats overlay is written (union hazard) ----
  __syncthreads();

  // ---- publish chunk matrix (packed bf16 row pairs, sigma-unscrambled) ----
  {
    unsigned* mw = s_pool + wv * 544;
    #pragma unroll
    for (int p = 0; p < 4; ++p) {
      mw[(sig(8 * h + 2 * p)      >> 1) * 34 + n] = Blo.u[p];
      mw[(sig(16 + 8 * h + 2 * p) >> 1) * 34 + n] = Bhi.u[p];
    }
  }
  #pragma unroll
  for (int d = 1; d < 64; d <<= 1) numer += __shfl_xor(numer, d);
  if (l == 0) { s_num[wv] = numer; s_K[wv] = Kacc; }
  __syncthreads();

  // ---- phase 2: wave 0 scans the 8 chunk matrices ----
  if (wv == 0) {
    const int t = n;
    const float em0 = emb[head * T + t];
    float sc0 = (startT[t] + em0) * L2E;
    float m0 = sc0;
    #pragma unroll
    for (int d = 1; d < 32; d <<= 1) m0 = fmaxf(m0, __shfl_xor(m0, d));
    float e = exp2f(sc0 - m0);
    float Mtot = m0;

    const unsigned sh = (t & 1) ? 0u : 16u;   // select row-half of packed word
    for (int c = 0; c < 8; ++c) {
      const unsigned* mw = s_pool + c * 544 + (t >> 1) * 34;
      float acc = 0.0f;
      #pragma unroll
      for (int q2 = 0; q2 < 16; ++q2) {
        uint2 w2 = *(const uint2*)(mw + 2 * q2);
        float vlo = __uint_as_float((w2.x << sh) & 0xFFFF0000u);
        float vhi = __uint_as_float((w2.y << sh) & 0xFFFF0000u);
        acc = fmaf(vlo, bcast_lane(e, 2 * q2), acc);
        acc = fmaf(vhi, bcast_lane(e, 2 * q2 + 1), acc);
      }
      e = acc;
      Mtot += (float)s_K[c];
      float mx = e;
      #pragma unroll
      for (int d = 1; d < 32; d <<= 1) mx = fmaxf(mx, __shfl_xor(mx, d));
      int E = (int)((__float_as_uint(mx) >> 23) & 0xffu);
      e *= __uint_as_float((unsigned)(254 - E) << 23);
      Mtot += (float)(E - 127);
    }

    float fv = e * exp2f(endT[t] * L2E);
    #pragma unroll
    for (int d = 1; d < 32; d <<= 1) fv += __shfl_xor(fv, d);
    float denom = (Mtot + log2f(fv)) * LN2f;

    if (l == 0) {
      if (cnt > 0) {
        float ntot = 0.0f;
        for (int wq = 0; wq < 8; ++wq) ntot += s_num[wq];
        int th = (int)s_tags[head], tt = (int)s_tags[tail];
        ntot += startT[th] + bcast_lane(em0, th) + endT[tt];
        atomicAdd(&ws[0], (denom - ntot) / ((float)cnt + 1e-6f));
        atomicAdd(&ws[1], 1.0f);
      }
      __threadfence();
      unsigned done = atomicAdd((unsigned*)ws + 2, 1u);
      if (done == (unsigned)(B - 1)) {
        __threadfence();
        out[0] = ws[0] / (ws[1] + 1e-6f);
      }
    }
  }
}

extern "C" void kernel_launch(void* const* d_in, const int* in_sizes, int n_in,
                              void* d_out, int out_size, void* d_ws, size_t ws_size,
                              hipStream_t stream) {
  const float* em     = (const float*)d_in[0];
  const int*   tags   = (const int*)d_in[1];
  const int*   mask   = (const int*)d_in[2];
  const float* startT = (const float*)d_in[3];
  const float* trans  = (const float*)d_in[4];
  const float* endT   = (const float*)d_in[5];
  float* out = (float*)d_out;
  float* ws  = (float*)d_ws;

  const int B = in_sizes[0] / (S * T);

  crf_zero<<<1, 1, 0, stream>>>(ws);
  crf_main<<<B, 512, 0, stream>>>(em, tags, mask, startT, trans, endT, ws, out, B);
}

// Round 8
// 262.672 us; speedup vs baseline: 1.0593x; 1.0321x over previous
//
#include <hip/hip_runtime.h>
#include <cstdint>

static constexpr int S = 1024;
static constexpr int T = 32;
static constexpr float L2E  = 1.4426950408889634f;  // log2(e)
static constexpr float LN2f = 0.6931471805599453f;  // ln(2)

typedef __attribute__((ext_vector_type(8)))  short  short8;
typedef __attribute__((ext_vector_type(16))) float  float16;
typedef __attribute__((ext_vector_type(2)))  float  f32x2;

union Frag { unsigned u[4]; short8 s; };
union D16  { float16 v; f32x2 p[8]; };   // MFMA acc viewed as 8 reg-pairs

__global__ void crf_zero(float* ws) {
  ws[0] = 0.0f; ws[1] = 0.0f; ((unsigned*)ws)[2] = 0u;
}

__device__ __forceinline__ float bcast_lane(float v, int k) {
  return __uint_as_float((unsigned)__builtin_amdgcn_readlane((int)__float_as_uint(v), k));
}

// single-instruction rounded pack: two f32 -> bf16x2 (lo = first arg).
__device__ __forceinline__ unsigned cvtpk(float lo, float hi) {
  unsigned r;
  asm("v_cvt_pk_bf16_f32 %0, %1, %2" : "=v"(r) : "v"(lo), "v"(hi));
  return r;
}

// async global->LDS, 16 B per lane: dest = wave-uniform base + lane*16.
__device__ __forceinline__ void gload16(const float* src, float* dst) {
  __builtin_amdgcn_global_load_lds(
      (const __attribute__((address_space(1))) unsigned int*)(src),
      (__attribute__((address_space(3))) unsigned int*)(dst),
      16, 0, 0);
}

// sigma: fixed row permutation mapping MFMA C-layout row slots onto B-operand
// row slots (swaps 4-blocks 1<->2 within each 16). With A pre-permuted
// (A'[m][k] = X[m][sig(k)]) the product is exact and D's packed pairs ARE the
// next B-operand - no lane data movement.
__device__ __forceinline__ int sig(int k) {
  int g2 = (k >> 2) & 3;
  if (g2 == 1) g2 = 2; else if (g2 == 2) g2 = 1;
  return (k & ~12) | (g2 << 2);
}

// Block = one batch (512 thr = 8 waves). Active range (head, tail] split into
// 8 equal chunks; wave w folds its chunk into a 32x32 matrix via MFMA in the
// linear 2^x domain (M <- diag(g_j) P^T M).
// R8: keep (512,8) for 4 blocks/CU (R5/R7 A/B: residency is worth +12 us even
// WITH spill), and cut true register demand below 64 so the spill (and its
// ~70% phantom VALU issue) disappears: (a) no pinned zero vector - D zeroed
// in the fold; (b) gw liveness halved (two 8-float phases); (c) diag-muls as
// f32x2 pair ops (v_pk_mul_f32 eligible).
__global__ __launch_bounds__(512, 8) void crf_main(
    const float* __restrict__ em, const int* __restrict__ tags,
    const int* __restrict__ mask, const float* __restrict__ startT,
    const float* __restrict__ trans, const float* __restrict__ endT,
    float* __restrict__ ws, float* __restrict__ out, int B)
{
  // 17408 B pool: fold phase = 8 waves x 512 f32 g-windows (16384 B);
  // publish/scan phase = 8 chunk mats x 544 u32 (17408 B). Barrier-separated.
  __shared__ __align__(16) unsigned s_pool[8 * 544];
  __shared__ float s_trans[1024];                      // 4 KiB
  __shared__ short s_tags[1024];                       // 2 KiB
  __shared__ unsigned long long s_mb[17];
  __shared__ int   s_head, s_tail, s_cnt, s_K[8];
  __shared__ float s_num[8];

  const int tid = threadIdx.x;
  const int l   = tid & 63;
  const int wv  = tid >> 6;
  const int b   = blockIdx.x;
  const int n   = l & 31;        // MFMA column / tag index
  const int h   = l >> 5;        // lane half

  const float* emb   = em   + (size_t)b * S * T;
  const int*   maskb = mask + (size_t)b * S;
  const int*   tagsb = tags + (size_t)b * S;

  // ---- cooperative staging: tags, trans, mask ballots ----
  for (int i = tid; i < 1024; i += 512) {
    s_tags[i]  = (short)tagsb[i];
    s_trans[i] = trans[i];
  }
  {
    unsigned long long b0 = __ballot(maskb[wv * 128 + l] != 0);
    unsigned long long b1 = __ballot(maskb[wv * 128 + 64 + l] != 0);
    if (l == 0) { s_mb[2 * wv] = b0; s_mb[2 * wv + 1] = b1; }
    if (tid == 0) s_mb[16] = 0ull;
  }

  // ---- A' = sigma-permuted P^T as bf16 frags (lane: m=n, k-slot=8h+2p+par) ----
  Frag Alo, Ahi;
  #pragma unroll
  for (int p = 0; p < 4; ++p) {
    int k0 = 8 * h + 2 * p;
    Alo.u[p] = cvtpk(exp2f(trans[sig(k0 + 0)      * T + n] * L2E),
                     exp2f(trans[sig(k0 + 1)      * T + n] * L2E));
    Ahi.u[p] = cvtpk(exp2f(trans[sig(16 + k0 + 0) * T + n] * L2E),
                     exp2f(trans[sig(16 + k0 + 1) * T + n] * L2E));
  }
  __syncthreads();

  if (wv == 0) {
    int first = 0x7fffffff, last = -1, pc = 0;
    if (l < 16) {
      unsigned long long w = s_mb[l];
      if (w) {
        first = 64 * l + (int)__builtin_ctzll(w);
        last  = 64 * l + 63 - (int)__builtin_clzll(w);
        pc    = (int)__builtin_popcountll(w);
      }
    }
    #pragma unroll
    for (int d = 1; d < 64; d <<= 1) {
      first = min(first, __shfl_xor(first, d));
      last  = max(last,  __shfl_xor(last,  d));
      pc   += __shfl_xor(pc, d);
    }
    if (l == 0) { s_head = first; s_tail = last; s_cnt = pc; }
  }
  __syncthreads();
  const int cnt  = s_cnt;
  const int head = (cnt > 0) ? s_head : 0;
  const int tail = (cnt > 0) ? s_tail : 0;

  // ---- equal-split chunk for this wave ----
  const int span = tail - head;
  const int Lc   = (span + 7) >> 3;
  const int c0   = head + 1 + wv * Lc;
  const int c1   = min(c0 + Lc, tail + 1);

  float* bcur = (float*)s_pool + wv * 512;   // ping-pong 8-step windows (wave-private)
  float* bnxt = bcur + 256;

  Frag Blo, Bhi;                    // running M in sigma-storage, init = I
  #pragma unroll
  for (int p = 0; p < 4; ++p) {
    int k0 = 8 * h + 2 * p;
    Blo.u[p] = ((sig(k0) == n)          ? 0x3F80u : 0u) |
               ((sig(k0 + 1) == n)      ? 0x3F800000u : 0u);
    Bhi.u[p] = ((sig(16 + k0) == n)     ? 0x3F80u : 0u) |
               ((sig(16 + k0 + 1) == n) ? 0x3F800000u : 0u);
  }
  int   Kacc  = 0;
  float numer = 0.0f;

#define FOLD(JJ, RSC) do {                                                   \
    D16 D;                                                                   \
    _Pragma("unroll")                                                        \
    for (int q_ = 0; q_ < 16; ++q_) D.v[q_] = 0.0f;                          \
    D.v = __builtin_amdgcn_mfma_f32_32x32x16_bf16(Alo.s, Blo.s, D.v, 0, 0, 0); \
    D.v = __builtin_amdgcn_mfma_f32_32x32x16_bf16(Ahi.s, Bhi.s, D.v, 0, 0, 0); \
    const f32x2* g2 = (const f32x2*)(gp + (JJ) * 32);                        \
    {                                                                        \
      f32x2 w0 = g2[2*h], w1 = g2[2*h + 1], w2 = g2[2*h + 4], w3 = g2[2*h + 5]; \
      D.p[0] *= w0; D.p[1] *= w1; D.p[2] *= w2; D.p[3] *= w3;                \
    }                                                                        \
    {                                                                        \
      f32x2 w4 = g2[2*h + 8], w5 = g2[2*h + 9], w6 = g2[2*h + 12], w7 = g2[2*h + 13]; \
      D.p[4] *= w4; D.p[5] *= w5; D.p[6] *= w6; D.p[7] *= w7;                \
    }                                                                        \
    if (RSC) {                                                               \
      float mx = fmaxf(fmaxf(fmaxf(D.v[0], D.v[1]), fmaxf(D.v[2], D.v[3])),  \
                       fmaxf(fmaxf(D.v[4], D.v[5]), fmaxf(D.v[6], D.v[7]))); \
      mx = fmaxf(mx, fmaxf(fmaxf(fmaxf(D.v[8], D.v[9]),  fmaxf(D.v[10], D.v[11])), \
                           fmaxf(fmaxf(D.v[12], D.v[13]), fmaxf(D.v[14], D.v[15])))); \
      mx = fmaxf(mx, __shfl_xor(mx, 32));   /* column-0 max (valid bound) */ \
      mx = __uint_as_float((unsigned)__builtin_amdgcn_readfirstlane(         \
               (int)__float_as_uint(mx)));                                   \
      int E = (int)((__float_as_uint(mx) >> 23) & 0xffu);                    \
      float sc = __uint_as_float((unsigned)(254 - E) << 23);                 \
      Kacc += E - 127;                                                       \
      _Pragma("unroll")                                                      \
      for (int q_ = 0; q_ < 16; ++q_) D.v[q_] *= sc;                         \
    }                                                                        \
    Blo.u[0] = cvtpk(D.v[0],  D.v[1]);  Blo.u[1] = cvtpk(D.v[2],  D.v[3]);   \
    Blo.u[2] = cvtpk(D.v[4],  D.v[5]);  Blo.u[3] = cvtpk(D.v[6],  D.v[7]);   \
    Bhi.u[0] = cvtpk(D.v[8],  D.v[9]);  Bhi.u[1] = cvtpk(D.v[10], D.v[11]);  \
    Bhi.u[2] = cvtpk(D.v[12], D.v[13]); Bhi.u[3] = cvtpk(D.v[14], D.v[15]);  \
  } while (0)

  // prologue: async-stage first 8-step window
  if (c0 < c1) {
    const int base = min(c0, S - 8);
    gload16(emb + (size_t)base * T + 4 * l, bcur);
  }

  for (int j0 = c0; j0 < c1; j0 += 8) {
    const int ns   = min(8, c1 - j0);
    const int base = min(j0, S - 8);
    const int d    = j0 - base;          // shift of j0 within loaded window

    // wait this wave's async load, then convert em -> g = 2^em in place
    // (each lane converts exactly the 16 B it loaded; wave-private buffer)
    asm volatile("s_waitcnt vmcnt(0)" ::: "memory");
    {
      float4 r = ((const float4*)bcur)[l];
      r.x = exp2f(r.x * L2E); r.y = exp2f(r.y * L2E);
      r.z = exp2f(r.z * L2E); r.w = exp2f(r.w * L2E);
      ((float4*)bcur)[l] = r;
    }

    // issue next window's async load now; folds below hide its latency
    if (j0 + 8 < c1) {
      const int nb = min(j0 + 8, S - 8);
      gload16(emb + (size_t)nb * T + 4 * l, bnxt);
    }

    const float* gp = bcur + d * 32;

    // 8-bit applied-mask at arbitrary offset j0 (funnel over ballot words)
    const int w = j0 >> 6, o = j0 & 63;
    unsigned long long bits = s_mb[w] >> o;
    if (o) bits |= s_mb[w + 1] << (64 - o);
    unsigned eff = (unsigned)(bits & 0xFFull) & (unsigned)((1u << ns) - 1u);

    // numerator: lanes 0..ns-1 take one step each (em recovered from f32 g)
    if (l < ns && ((eff >> l) & 1u)) {
      int j  = j0 + l;
      int tg = (int)s_tags[j], tp = (int)s_tags[j - 1];
      float gval = gp[l * 32 + tg];
      numer += s_trans[tp * T + tg] + log2f(gval) * LN2f;
    }

    if (eff == 0xFFu) {
      #pragma unroll
      for (int jj = 0; jj < 8; ++jj) FOLD(jj, (jj == 7));
    } else {
      for (int jj = 0; jj < ns; ++jj)
        if ((eff >> jj) & 1u) FOLD(jj, true);
    }

    float* tmp = bcur; bcur = bnxt; bnxt = tmp;
  }
#undef FOLD

  // ---- all folds done before the mats overlay is written (union hazard) ----
  __syncthreads();

  // ---- publish chunk matrix (packed bf16 row pairs, sigma-unscrambled) ----
  {
    unsigned* mw = s_pool + wv * 544;
    #pragma unroll
    for (int p = 0; p < 4; ++p) {
      mw[(sig(8 * h + 2 * p)      >> 1) * 34 + n] = Blo.u[p];
      mw[(sig(16 + 8 * h + 2 * p) >> 1) * 34 + n] = Bhi.u[p];
    }
  }
  #pragma unroll
  for (int d = 1; d < 64; d <<= 1) numer += __shfl_xor(numer, d);
  if (l == 0) { s_num[wv] = numer; s_K[wv] = Kacc; }
  __syncthreads();

  // ---- phase 2: wave 0 scans the 8 chunk matrices ----
  if (wv == 0) {
    const int t = n;
    const float em0 = emb[head * T + t];
    float sc0 = (startT[t] + em0) * L2E;
    float m0 = sc0;
    #pragma unroll
    for (int d = 1; d < 32; d <<= 1) m0 = fmaxf(m0, __shfl_xor(m0, d));
    float e = exp2f(sc0 - m0);
    float Mtot = m0;

    const unsigned sh = (t & 1) ? 0u : 16u;   // select row-half of packed word
    for (int c = 0; c < 8; ++c) {
      const unsigned* mw = s_pool + c * 544 + (t >> 1) * 34;
      float acc = 0.0f;
      #pragma unroll
      for (int q2 = 0; q2 < 16; ++q2) {
        uint2 w2 = *(const uint2*)(mw + 2 * q2);
        float vlo = __uint_as_float((w2.x << sh) & 0xFFFF0000u);
        float vhi = __uint_as_float((w2.y << sh) & 0xFFFF0000u);
        acc = fmaf(vlo, bcast_lane(e, 2 * q2), acc);
        acc = fmaf(vhi, bcast_lane(e, 2 * q2 + 1), acc);
      }
      e = acc;
      Mtot += (float)s_K[c];
      float mx = e;
      #pragma unroll
      for (int d = 1; d < 32; d <<= 1) mx = fmaxf(mx, __shfl_xor(mx, d));
      int E = (int)((__float_as_uint(mx) >> 23) & 0xffu);
      e *= __uint_as_float((unsigned)(254 - E) << 23);
      Mtot += (float)(E - 127);
    }

    float fv = e * exp2f(endT[t] * L2E);
    #pragma unroll
    for (int d = 1; d < 32; d <<= 1) fv += __shfl_xor(fv, d);
    float denom = (Mtot + log2f(fv)) * LN2f;

    if (l == 0) {
      if (cnt > 0) {
        float ntot = 0.0f;
        for (int wq = 0; wq < 8; ++wq) ntot += s_num[wq];
        int th = (int)s_tags[head], tt = (int)s_tags[tail];
        ntot += startT[th] + bcast_lane(em0, th) + endT[tt];
        atomicAdd(&ws[0], (denom - ntot) / ((float)cnt + 1e-6f));
        atomicAdd(&ws[1], 1.0f);
      }
      __threadfence();
      unsigned done = atomicAdd((unsigned*)ws + 2, 1u);
      if (done == (unsigned)(B - 1)) {
        __threadfence();
        out[0] = ws[0] / (ws[1] + 1e-6f);
      }
    }
  }
}

extern "C" void kernel_launch(void* const* d_in, const int* in_sizes, int n_in,
                              void* d_out, int out_size, void* d_ws, size_t ws_size,
                              hipStream_t stream) {
  const float* em     = (const float*)d_in[0];
  const int*   tags   = (const int*)d_in[1];
  const int*   mask   = (const int*)d_in[2];
  const float* startT = (const float*)d_in[3];
  const float* trans  = (const float*)d_in[4];
  const float* endT   = (const float*)d_in[5];
  float* out = (float*)d_out;
  float* ws  = (float*)d_ws;

  const int B = in_sizes[0] / (S * T);

  crf_zero<<<1, 1, 0, stream>>>(ws);
  crf_main<<<B, 512, 0, stream>>>(em, tags, mask, startT, trans, endT, ws, out, B);
}